// Round 4
// baseline (357.491 us; speedup 1.0000x reference)
//
#include <hip/hip_runtime.h>
#include <hip/hip_bf16.h>

#define NB 512
#define CIN 32
#define LEN 512
#define NE 8
#define NPOOL 16
#define DIN 16384
#define DOUT 768
#define HD 1024
#define F1 128

#define MT 128      // GEMM M tile
#define NT 64       // GEMM N tile
#define BK 64       // K step

typedef __attribute__((ext_vector_type(4))) float f32x4;
typedef __attribute__((ext_vector_type(8))) short s16x8;
typedef __attribute__((ext_vector_type(4))) unsigned int u32x4;

__device__ __forceinline__ float gelu_erf(float v) {
    return 0.5f * v * (1.0f + erff(v * 0.70710678118654752f));
}

__device__ __forceinline__ unsigned cvt_pk(float lo, float hi) {
    unsigned r;
    asm volatile("v_cvt_pk_bf16_f32 %0, %1, %2" : "=v"(r) : "v"(lo), "v"(hi));
    return r;
}

__device__ __forceinline__ unsigned short f2bf_u(float f) {
    union { float f; unsigned u; } x; x.f = f;
    unsigned r = x.u + 0x7fffu + ((x.u >> 16) & 1u);
    return (unsigned short)(r >> 16);
}

// ---------------- Kernel A: conv1d(k=3,pad=1) + GELU + avgpool(32) + BN (+ cnt zeroing) ----
__global__ __launch_bounds__(512) void krouter_conv(
    const float* __restrict__ x, const float* __restrict__ cw, const float* __restrict__ cb,
    const float* __restrict__ bng, const float* __restrict__ bnb,
    const float* __restrict__ bnm, const float* __restrict__ bnv,
    float* __restrict__ h, int* __restrict__ cnt)
{
    __shared__ float xs[CIN * LEN];   // 64KB, XOR-swizzled in 16B units along l
    int b = blockIdx.x;
    int t = threadIdx.x;
    if (b == 0 && t < NE) cnt[t] = 0;   // zero expert counters (conv runs before fc)

    const f32x4* xg = (const f32x4*)(x + (size_t)b * DIN);
    #pragma unroll
    for (int u = 0; u < 8; ++u) {
        int fi = t + 512 * u;
        f32x4 v = xg[fi];
        int e0 = fi * 4;
        int ci = e0 >> 9, l = e0 & 511;
        int byte = ci * 2048 + ((l * 4) ^ ((((unsigned)l >> 5) & 7u) << 4));
        *(f32x4*)((char*)xs + byte) = v;
    }
    __syncthreads();

    int p  = t & 15;
    int cq = t >> 4;
    int co0 = cq * 2, co1 = co0 + 1;
    int l0 = p * 32;

    float sa[32], sb[32];
    #pragma unroll
    for (int i = 0; i < 32; ++i) { sa[i] = 0.f; sb[i] = 0.f; }

    for (int ci = 0; ci < CIN; ++ci) {
        float f[40];
        #pragma unroll
        for (int u = 0; u < 10; ++u) {
            int l = l0 - 4 + 4 * u;
            int lc = min(max(l, 0), 508);
            int byte = ci * 2048 + ((lc * 4) ^ ((((unsigned)lc >> 5) & 7u) << 4));
            f32x4 v = *(const f32x4*)((const char*)xs + byte);
            f[4*u+0] = v[0]; f[4*u+1] = v[1]; f[4*u+2] = v[2]; f[4*u+3] = v[3];
        }
        if (p == 0)  f[3]  = 0.f;
        if (p == 15) f[36] = 0.f;
        float wa0 = cw[co0*96 + ci*3 + 0], wa1 = cw[co0*96 + ci*3 + 1], wa2 = cw[co0*96 + ci*3 + 2];
        float wb0 = cw[co1*96 + ci*3 + 0], wb1 = cw[co1*96 + ci*3 + 1], wb2 = cw[co1*96 + ci*3 + 2];
        #pragma unroll
        for (int i = 0; i < 32; ++i) {
            sa[i] = fmaf(f[i+3], wa0, fmaf(f[i+4], wa1, fmaf(f[i+5], wa2, sa[i])));
            sb[i] = fmaf(f[i+3], wb0, fmaf(f[i+4], wb1, fmaf(f[i+5], wb2, sb[i])));
        }
    }

    float ba = cb[co0], bbv = cb[co1];
    float ma = 0.f, mb = 0.f;
    #pragma unroll
    for (int i = 0; i < 32; ++i) { ma += gelu_erf(sa[i] + ba); mb += gelu_erf(sb[i] + bbv); }
    ma *= (1.f / 32.f); mb *= (1.f / 32.f);

    int oa = co0 * NPOOL + p, ob = co1 * NPOOL + p;
    float ra = (ma - bnm[oa]) * rsqrtf(bnv[oa] + 1e-5f) * bng[oa] + bnb[oa];
    float rb = (mb - bnm[ob]) * rsqrtf(bnv[ob] + 1e-5f) * bng[ob] + bnb[ob];
    h[(size_t)b * HD + oa] = ra;
    h[(size_t)b * HD + ob] = rb;
}

// ---------------- Kernel B: fc1+GELU, fc2, gumbel softmax, top-2, expert row lists ----------
__global__ __launch_bounds__(256) void krouter_fc(
    const float* __restrict__ h, const float* __restrict__ f1w, const float* __restrict__ f1b,
    const float* __restrict__ f2w, const float* __restrict__ f2b,
    const float* __restrict__ gu,
    int* __restrict__ top2e, float* __restrict__ top2w,
    int* __restrict__ cnt, int* __restrict__ rowlist, float* __restrict__ roww)
{
    __shared__ float hs[8 * HD];
    __shared__ float h1s[8 * F1];
    __shared__ float lg[8 * NE];

    int bb = blockIdx.x * 8;
    int t = threadIdx.x;

    const f32x4* hg = (const f32x4*)(h + (size_t)bb * HD);
    f32x4* hs4 = (f32x4*)hs;
    #pragma unroll
    for (int u = 0; u < 8; ++u) hs4[t + 256 * u] = hg[t + 256 * u];
    __syncthreads();

    int j = t & 127;
    int pr = t >> 7;
    float acc[4] = {0.f, 0.f, 0.f, 0.f};
    const f32x4* w4 = (const f32x4*)(f1w + (size_t)j * HD);
    for (int k4 = 0; k4 < 256; ++k4) {
        f32x4 w = w4[k4];
        #pragma unroll
        for (int g = 0; g < 4; ++g) {
            f32x4 hv = hs4[(pr * 4 + g) * 256 + k4];
            acc[g] += w[0]*hv[0] + w[1]*hv[1] + w[2]*hv[2] + w[3]*hv[3];
        }
    }
    float bj = f1b[j];
    #pragma unroll
    for (int g = 0; g < 4; ++g) h1s[(pr * 4 + g) * F1 + j] = gelu_erf(acc[g] + bj);
    __syncthreads();

    if (t < 64) {
        int bi = t >> 3, e = t & 7;
        float s = f2b[e];
        const float* w = f2w + e * F1;
        const float* hh = h1s + bi * F1;
        #pragma unroll 8
        for (int k = 0; k < F1; ++k) s += hh[k] * w[k];
        lg[bi * NE + e] = s;
    }
    __syncthreads();

    if (t < 8) {
        int bi = t; int b = bb + bi;
        float r[NE];
        float mx = -1e30f;
        #pragma unroll
        for (int e = 0; e < NE; ++e) {
            float g = -logf(-logf(gu[b * NE + e]));
            r[e] = lg[bi * NE + e] + g;
            mx = fmaxf(mx, r[e]);
        }
        float sum = 0.f;
        #pragma unroll
        for (int e = 0; e < NE; ++e) { r[e] = expf(r[e] - mx); sum += r[e]; }
        float inv = 1.f / sum;
        #pragma unroll
        for (int e = 0; e < NE; ++e) r[e] *= inv;
        int e0 = 0; float v0 = r[0];
        #pragma unroll
        for (int e = 1; e < NE; ++e) if (r[e] > v0) { v0 = r[e]; e0 = e; }
        int e1 = -1; float v1 = -1.f;
        #pragma unroll
        for (int e = 0; e < NE; ++e) { if (e == e0) continue; if (r[e] > v1) { v1 = r[e]; e1 = e; } }
        float den = v0 + v1 + 1e-8f;
        float w0 = v0 / den, w1 = v1 / den;
        top2e[b * 2 + 0] = e0; top2e[b * 2 + 1] = e1;
        top2w[b * 2 + 0] = w0; top2w[b * 2 + 1] = w1;
        int p0 = atomicAdd(&cnt[e0], 1);
        rowlist[e0 * NB + p0] = b * 2 + 0; roww[e0 * NB + p0] = w0;
        int p1 = atomicAdd(&cnt[e1], 1);
        rowlist[e1 * NB + p1] = b * 2 + 1; roww[e1 * NB + p1] = w1;
    }
}

// ---------------- Kernel C: gathered expert GEMM, bf16 MFMA, small blocks, T14 pipeline ----
// grid = 8e * 12nt * nkc, block = 256 (4 waves: 2m x 2n), wave tile 64x32
__global__ __launch_bounds__(256, 4) void kgemm(
    const float* __restrict__ x, const float* __restrict__ ew,
    const int* __restrict__ cnt, const int* __restrict__ rowlist, const float* __restrict__ roww,
    unsigned short* __restrict__ ypart, int nkc, int kch)
{
    int bid = blockIdx.x;
    int kc = bid % nkc;
    int nt = (bid / nkc) % 12;
    int e  = bid / (nkc * 12);
    int cn = cnt[e];
    if (cn <= 0) return;

    __shared__ __align__(16) short As[MT * BK];   // 16KB, XOR swizzle
    __shared__ __align__(16) short Bs[NT * BK];   // 8KB, W^T tile

    int t = threadIdx.x;
    int wid = t >> 6, lane = t & 63;
    int wm = wid >> 1, wn = wid & 1;
    int g = lane >> 4;
    int NS = kch / BK;
    int k0 = kc * kch;

    // B staging assignment: col n = t&63, k-group = t>>6 (16 k's each)
    int bn = t & 63, bkg = t >> 6;
    const float* bwp = ew + (size_t)e * ((size_t)DIN * DOUT)
                          + (size_t)(k0 + bkg * 16) * DOUT + nt * NT + bn;

    for (int row0 = 0; row0 < cn; row0 += MT) {
        int mloc = min(MT, cn - row0);

        // A staging assignment: row = t>>1 (0..127), half = t&1 (32 floats each)
        int ar = t >> 1, ah = t & 1;
        int arc = min(ar, mloc - 1);
        int ent_a = rowlist[e * NB + row0 + arc];
        const float* axp = x + (size_t)(ent_a >> 1) * DIN + k0 + ah * 32;
        bool ado = (ar < mloc);
        bool wact = (wm * 64 < mloc);

        f32x4 acc[4][2];
        #pragma unroll
        for (int i = 0; i < 4; ++i)
            #pragma unroll
            for (int jj = 0; jj < 2; ++jj) acc[i][jj] = (f32x4){0.f, 0.f, 0.f, 0.f};

        f32x4 Ar[8]; float Br[16];

        auto issue_loads = [&](int s) {
            const f32x4* p = (const f32x4*)(axp + s * BK);
            if (ado) {
                #pragma unroll
                for (int u = 0; u < 8; ++u) Ar[u] = p[u];
            }
            #pragma unroll
            for (int i = 0; i < 16; ++i)
                Br[i] = bwp[(size_t)(s * BK + i) * DOUT];
        };
        auto cvt_store = [&]() {
            if (ado) {
                #pragma unroll
                for (int u = 0; u < 4; ++u) {
                    u32x4 pk;
                    pk[0] = cvt_pk(Ar[2*u][0], Ar[2*u][1]);
                    pk[1] = cvt_pk(Ar[2*u][2], Ar[2*u][3]);
                    pk[2] = cvt_pk(Ar[2*u+1][0], Ar[2*u+1][1]);
                    pk[3] = cvt_pk(Ar[2*u+1][2], Ar[2*u+1][3]);
                    int colb = (ah * 32 + u * 8) * 2;
                    *(u32x4*)((char*)As + ar * 128 + (colb ^ ((ar & 7) << 4))) = pk;
                }
            }
            #pragma unroll
            for (int u = 0; u < 2; ++u) {
                u32x4 pk;
                pk[0] = cvt_pk(Br[u*8+0], Br[u*8+1]);
                pk[1] = cvt_pk(Br[u*8+2], Br[u*8+3]);
                pk[2] = cvt_pk(Br[u*8+4], Br[u*8+5]);
                pk[3] = cvt_pk(Br[u*8+6], Br[u*8+7]);
                int colb = (bkg * 16 + u * 8) * 2;
                *(u32x4*)((char*)Bs + bn * 128 + (colb ^ ((bn & 7) << 4))) = pk;
            }
        };

        // prologue: tile 0
        issue_loads(0);
        cvt_store();
        __syncthreads();

        for (int s = 0; s < NS; ++s) {
            if (s + 1 < NS) issue_loads(s + 1);   // in flight across the MFMA phase

            if (wact) {
                #pragma unroll
                for (int kk = 0; kk < 2; ++kk) {
                    int colb = kk * 64 + g * 16;
                    s16x8 af[4], bfr[2];
                    #pragma unroll
                    for (int mi = 0; mi < 4; ++mi) {
                        int m = wm * 64 + mi * 16 + (lane & 15);
                        af[mi] = *(const s16x8*)((const char*)As + m * 128 + (colb ^ ((m & 7) << 4)));
                    }
                    #pragma unroll
                    for (int ni = 0; ni < 2; ++ni) {
                        int n = wn * 32 + ni * 16 + (lane & 15);
                        bfr[ni] = *(const s16x8*)((const char*)Bs + n * 128 + (colb ^ ((n & 7) << 4)));
                    }
                    #pragma unroll
                    for (int mi = 0; mi < 4; ++mi)
                        #pragma unroll
                        for (int ni = 0; ni < 2; ++ni)
                            acc[mi][ni] = __builtin_amdgcn_mfma_f32_16x16x32_bf16(af[mi], bfr[ni], acc[mi][ni], 0, 0, 0);
                }
            }
            __syncthreads();                       // all waves done reading LDS
            if (s + 1 < NS) cvt_store();           // overwrite with tile s+1
            __syncthreads();                       // tile s+1 visible
        }

        // ---- epilogue: apply gate weight, bf16 scatter to per-(slot,kc) partial plane ----
        if (wact) {
            #pragma unroll
            for (int mi = 0; mi < 4; ++mi) {
                #pragma unroll
                for (int rg = 0; rg < 4; ++rg) {
                    int m = wm * 64 + mi * 16 + g * 4 + rg;
                    if (m < mloc) {
                        int ent = rowlist[e * NB + row0 + m];
                        float wgt = roww[e * NB + row0 + m];
                        int ob = ent >> 1, slot = ent & 1;
                        unsigned short* dst = ypart + ((size_t)(slot * nkc + kc) * NB + ob) * DOUT
                                            + nt * NT + wn * 32 + (lane & 15);
                        #pragma unroll
                        for (int ni = 0; ni < 2; ++ni)
                            dst[ni * 16] = f2bf_u(acc[mi][ni][rg] * wgt);
                    }
                }
            }
        }
    }
}

// ---------------- Kernel D: combine bf16 partial planes + weighted expert bias ------------
__global__ __launch_bounds__(256) void kcombine(
    const unsigned short* __restrict__ ypart,
    const int* __restrict__ top2e, const float* __restrict__ top2w,
    const float* __restrict__ eb, float* __restrict__ out, int nplanes)
{
    int b = blockIdx.y;
    int n = blockIdx.x * 256 + threadIdx.x;
    float s = 0.f;
    for (int p = 0; p < nplanes; ++p) {
        unsigned v = ypart[((size_t)p * NB + b) * DOUT + n];
        union { unsigned u; float f; } c; c.u = v << 16;
        s += c.f;
    }
    int e0 = top2e[b * 2], e1 = top2e[b * 2 + 1];
    float w0 = top2w[b * 2], w1 = top2w[b * 2 + 1];
    s += w0 * eb[e0 * DOUT + n] + w1 * eb[e1 * DOUT + n];
    out[(size_t)b * DOUT + n] = s;
}

extern "C" void kernel_launch(void* const* d_in, const int* in_sizes, int n_in,
                              void* d_out, int out_size, void* d_ws, size_t ws_size,
                              hipStream_t stream)
{
    const float* x   = (const float*)d_in[0];
    const float* gu  = (const float*)d_in[1];
    const float* cw  = (const float*)d_in[2];
    const float* cb  = (const float*)d_in[3];
    const float* bng = (const float*)d_in[4];
    const float* bnb = (const float*)d_in[5];
    const float* bnm = (const float*)d_in[6];
    const float* bnv = (const float*)d_in[7];
    const float* f1w = (const float*)d_in[8];
    const float* f1b = (const float*)d_in[9];
    const float* f2w = (const float*)d_in[10];
    const float* f2b = (const float*)d_in[11];
    const float* ew  = (const float*)d_in[12];
    const float* eb  = (const float*)d_in[13];

    int nkc = (ws_size >= (size_t)40 * 1024 * 1024) ? 16 : 8;
    int kch = DIN / nkc;

    char* ws = (char*)d_ws;
    size_t off = 0;
    float* h       = (float*)(ws + off); off += (size_t)NB * HD * 4;
    int*   top2e   = (int*)(ws + off);   off += (size_t)NB * 2 * 4;
    float* top2w   = (float*)(ws + off); off += (size_t)NB * 2 * 4;
    int*   cnt     = (int*)(ws + off);   off += 256;
    int*   rowlist = (int*)(ws + off);   off += (size_t)NE * NB * 4;
    float* roww    = (float*)(ws + off); off += (size_t)NE * NB * 4;
    unsigned short* ypart = (unsigned short*)(ws + off);
    off += (size_t)2 * nkc * NB * DOUT * 2;

    krouter_conv<<<NB, 512, 0, stream>>>(x, cw, cb, bng, bnb, bnm, bnv, h, cnt);
    krouter_fc<<<NB / 8, 256, 0, stream>>>(h, f1w, f1b, f2w, f2b, gu,
                                           top2e, top2w, cnt, rowlist, roww);
    kgemm<<<NE * 12 * nkc, 256, 0, stream>>>(x, ew, cnt, rowlist, roww, ypart, nkc, kch);
    kcombine<<<dim3(3, NB), 256, 0, stream>>>(ypart, top2e, top2w, eb, (float*)d_out, 2 * nkc);
}

// Round 5
// 315.881 us; speedup vs baseline: 1.1317x; 1.1317x over previous
//
#include <hip/hip_runtime.h>
#include <hip/hip_bf16.h>

#define NB 512
#define CIN 32
#define LEN 512
#define NE 8
#define NPOOL 16
#define DIN 16384
#define DOUT 768
#define HD 1024
#define F1 128

#define MT 128      // GEMM M tile
#define NT 64       // GEMM N tile
#define BK 64       // K step

typedef __attribute__((ext_vector_type(4))) float f32x4;
typedef __attribute__((ext_vector_type(8))) short s16x8;
typedef __attribute__((ext_vector_type(4))) unsigned int u32x4;

__device__ __forceinline__ float gelu_erf(float v) {
    return 0.5f * v * (1.0f + erff(v * 0.70710678118654752f));
}

__device__ __forceinline__ unsigned cvt_pk(float lo, float hi) {
    unsigned r;
    asm volatile("v_cvt_pk_bf16_f32 %0, %1, %2" : "=v"(r) : "v"(lo), "v"(hi));
    return r;
}

__device__ __forceinline__ unsigned short f2bf_u(float f) {
    union { float f; unsigned u; } x; x.f = f;
    unsigned r = x.u + 0x7fffu + ((x.u >> 16) & 1u);
    return (unsigned short)(r >> 16);
}

// ---------------- Kernel A: conv1d(k=3,pad=1) + GELU + avgpool(32) + BN (+ cnt zeroing) ----
__global__ __launch_bounds__(512) void krouter_conv(
    const float* __restrict__ x, const float* __restrict__ cw, const float* __restrict__ cb,
    const float* __restrict__ bng, const float* __restrict__ bnb,
    const float* __restrict__ bnm, const float* __restrict__ bnv,
    float* __restrict__ h, int* __restrict__ cnt)
{
    __shared__ float xs[CIN * LEN];   // 64KB, XOR-swizzled in 16B units along l
    int b = blockIdx.x;
    int t = threadIdx.x;
    if (b == 0 && t < NE) cnt[t] = 0;

    const f32x4* xg = (const f32x4*)(x + (size_t)b * DIN);
    #pragma unroll
    for (int u = 0; u < 8; ++u) {
        int fi = t + 512 * u;
        f32x4 v = xg[fi];
        int e0 = fi * 4;
        int ci = e0 >> 9, l = e0 & 511;
        int byte = ci * 2048 + ((l * 4) ^ ((((unsigned)l >> 5) & 7u) << 4));
        *(f32x4*)((char*)xs + byte) = v;
    }
    __syncthreads();

    int p  = t & 15;
    int cq = t >> 4;
    int co0 = cq * 2, co1 = co0 + 1;
    int l0 = p * 32;

    float sa[32], sb[32];
    #pragma unroll
    for (int i = 0; i < 32; ++i) { sa[i] = 0.f; sb[i] = 0.f; }

    for (int ci = 0; ci < CIN; ++ci) {
        float f[40];
        #pragma unroll
        for (int u = 0; u < 10; ++u) {
            int l = l0 - 4 + 4 * u;
            int lc = min(max(l, 0), 508);
            int byte = ci * 2048 + ((lc * 4) ^ ((((unsigned)lc >> 5) & 7u) << 4));
            f32x4 v = *(const f32x4*)((const char*)xs + byte);
            f[4*u+0] = v[0]; f[4*u+1] = v[1]; f[4*u+2] = v[2]; f[4*u+3] = v[3];
        }
        if (p == 0)  f[3]  = 0.f;
        if (p == 15) f[36] = 0.f;
        float wa0 = cw[co0*96 + ci*3 + 0], wa1 = cw[co0*96 + ci*3 + 1], wa2 = cw[co0*96 + ci*3 + 2];
        float wb0 = cw[co1*96 + ci*3 + 0], wb1 = cw[co1*96 + ci*3 + 1], wb2 = cw[co1*96 + ci*3 + 2];
        #pragma unroll
        for (int i = 0; i < 32; ++i) {
            sa[i] = fmaf(f[i+3], wa0, fmaf(f[i+4], wa1, fmaf(f[i+5], wa2, sa[i])));
            sb[i] = fmaf(f[i+3], wb0, fmaf(f[i+4], wb1, fmaf(f[i+5], wb2, sb[i])));
        }
    }

    float ba = cb[co0], bbv = cb[co1];
    float ma = 0.f, mb = 0.f;
    #pragma unroll
    for (int i = 0; i < 32; ++i) { ma += gelu_erf(sa[i] + ba); mb += gelu_erf(sb[i] + bbv); }
    ma *= (1.f / 32.f); mb *= (1.f / 32.f);

    int oa = co0 * NPOOL + p, ob = co1 * NPOOL + p;
    float ra = (ma - bnm[oa]) * rsqrtf(bnv[oa] + 1e-5f) * bng[oa] + bnb[oa];
    float rb = (mb - bnm[ob]) * rsqrtf(bnv[ob] + 1e-5f) * bng[ob] + bnb[ob];
    h[(size_t)b * HD + oa] = ra;
    h[(size_t)b * HD + ob] = rb;
}

// ---------------- Kernel B: fc1+GELU, fc2, gumbel softmax, top-2, expert row lists ----------
__global__ __launch_bounds__(256) void krouter_fc(
    const float* __restrict__ h, const float* __restrict__ f1w, const float* __restrict__ f1b,
    const float* __restrict__ f2w, const float* __restrict__ f2b,
    const float* __restrict__ gu,
    int* __restrict__ top2e, float* __restrict__ top2w,
    int* __restrict__ cnt, int* __restrict__ rowlist, float* __restrict__ roww)
{
    __shared__ float hs[8 * HD];
    __shared__ float h1s[8 * F1];
    __shared__ float lg[8 * NE];

    int bb = blockIdx.x * 8;
    int t = threadIdx.x;

    const f32x4* hg = (const f32x4*)(h + (size_t)bb * HD);
    f32x4* hs4 = (f32x4*)hs;
    #pragma unroll
    for (int u = 0; u < 8; ++u) hs4[t + 256 * u] = hg[t + 256 * u];
    __syncthreads();

    int j = t & 127;
    int pr = t >> 7;
    float acc[4] = {0.f, 0.f, 0.f, 0.f};
    const f32x4* w4 = (const f32x4*)(f1w + (size_t)j * HD);
    for (int k4 = 0; k4 < 256; ++k4) {
        f32x4 w = w4[k4];
        #pragma unroll
        for (int g = 0; g < 4; ++g) {
            f32x4 hv = hs4[(pr * 4 + g) * 256 + k4];
            acc[g] += w[0]*hv[0] + w[1]*hv[1] + w[2]*hv[2] + w[3]*hv[3];
        }
    }
    float bj = f1b[j];
    #pragma unroll
    for (int g = 0; g < 4; ++g) h1s[(pr * 4 + g) * F1 + j] = gelu_erf(acc[g] + bj);
    __syncthreads();

    if (t < 64) {
        int bi = t >> 3, e = t & 7;
        float s = f2b[e];
        const float* w = f2w + e * F1;
        const float* hh = h1s + bi * F1;
        #pragma unroll 8
        for (int k = 0; k < F1; ++k) s += hh[k] * w[k];
        lg[bi * NE + e] = s;
    }
    __syncthreads();

    if (t < 8) {
        int bi = t; int b = bb + bi;
        float r[NE];
        float mx = -1e30f;
        #pragma unroll
        for (int e = 0; e < NE; ++e) {
            float g = -logf(-logf(gu[b * NE + e]));
            r[e] = lg[bi * NE + e] + g;
            mx = fmaxf(mx, r[e]);
        }
        float sum = 0.f;
        #pragma unroll
        for (int e = 0; e < NE; ++e) { r[e] = expf(r[e] - mx); sum += r[e]; }
        float inv = 1.f / sum;
        #pragma unroll
        for (int e = 0; e < NE; ++e) r[e] *= inv;
        int e0 = 0; float v0 = r[0];
        #pragma unroll
        for (int e = 1; e < NE; ++e) if (r[e] > v0) { v0 = r[e]; e0 = e; }
        int e1 = -1; float v1 = -1.f;
        #pragma unroll
        for (int e = 0; e < NE; ++e) { if (e == e0) continue; if (r[e] > v1) { v1 = r[e]; e1 = e; } }
        float den = v0 + v1 + 1e-8f;
        float w0 = v0 / den, w1 = v1 / den;
        top2e[b * 2 + 0] = e0; top2e[b * 2 + 1] = e1;
        top2w[b * 2 + 0] = w0; top2w[b * 2 + 1] = w1;
        int p0 = atomicAdd(&cnt[e0], 1);
        rowlist[e0 * NB + p0] = b * 2 + 0; roww[e0 * NB + p0] = w0;
        int p1 = atomicAdd(&cnt[e1], 1);
        rowlist[e1 * NB + p1] = b * 2 + 1; roww[e1 * NB + p1] = w1;
    }
}

// ---------------- Kernel C: gathered expert GEMM, bf16 MFMA, dbuf LDS, 1 barrier/step -----
// grid = 8e * 12nt * nkc, block = 256 (4 waves: 2m x 2n), wave tile 64x32
// launch_bounds(256,3): VGPR cap ~168 (NO spills — R4's (256,4)=64 VGPR spilled the pipeline)
__global__ __launch_bounds__(256, 3) void kgemm(
    const float* __restrict__ x, const float* __restrict__ ew,
    const int* __restrict__ cnt, const int* __restrict__ rowlist, const float* __restrict__ roww,
    unsigned short* __restrict__ ypart, int nkc, int kch)
{
    int bid = blockIdx.x;
    int kc = bid % nkc;
    int nt = (bid / nkc) % 12;
    int e  = bid / (nkc * 12);
    int cn = cnt[e];
    if (cn <= 0) return;

    __shared__ __align__(16) short As[2][MT * BK];   // 2 x 16KB, XOR swizzle
    __shared__ __align__(16) short Bs[2][NT * BK];   // 2 x 8KB,  W^T tile

    int t = threadIdx.x;
    int wid = t >> 6, lane = t & 63;
    int wm = wid >> 1, wn = wid & 1;
    int g = lane >> 4;
    int NS = kch / BK;
    int k0 = kc * kch;

    // B staging assignment: col n = t&63, k-group = t>>6 (16 k's each)
    int bn = t & 63, bkg = t >> 6;
    const float* bwp = ew + (size_t)e * ((size_t)DIN * DOUT)
                          + (size_t)(k0 + bkg * 16) * DOUT + nt * NT + bn;

    for (int row0 = 0; row0 < cn; row0 += MT) {
        int mloc = min(MT, cn - row0);

        // A staging assignment: row = t>>1 (0..127), half = t&1 (32 floats each)
        int ar = t >> 1, ah = t & 1;
        int arc = min(ar, mloc - 1);
        int ent_a = rowlist[e * NB + row0 + arc];
        const float* axp = x + (size_t)(ent_a >> 1) * DIN + k0 + ah * 32;
        bool ado = (ar < mloc);
        bool wact = (wm * 64 < mloc);

        f32x4 acc[4][2];
        #pragma unroll
        for (int i = 0; i < 4; ++i)
            #pragma unroll
            for (int jj = 0; jj < 2; ++jj) acc[i][jj] = (f32x4){0.f, 0.f, 0.f, 0.f};

        f32x4 Ar[8]; float Br[16];

        auto issue_loads = [&](int s) {
            const f32x4* p = (const f32x4*)(axp + s * BK);
            if (ado) {
                #pragma unroll
                for (int u = 0; u < 8; ++u) Ar[u] = p[u];
            }
            #pragma unroll
            for (int i = 0; i < 16; ++i)
                Br[i] = bwp[(size_t)(s * BK + i) * DOUT];
        };
        auto cvt_store = [&](int bi) {
            if (ado) {
                #pragma unroll
                for (int u = 0; u < 4; ++u) {
                    u32x4 pk;
                    pk[0] = cvt_pk(Ar[2*u][0], Ar[2*u][1]);
                    pk[1] = cvt_pk(Ar[2*u][2], Ar[2*u][3]);
                    pk[2] = cvt_pk(Ar[2*u+1][0], Ar[2*u+1][1]);
                    pk[3] = cvt_pk(Ar[2*u+1][2], Ar[2*u+1][3]);
                    int colb = (ah * 32 + u * 8) * 2;
                    *(u32x4*)((char*)As[bi] + ar * 128 + (colb ^ ((ar & 7) << 4))) = pk;
                }
            }
            #pragma unroll
            for (int u = 0; u < 2; ++u) {
                u32x4 pk;
                pk[0] = cvt_pk(Br[u*8+0], Br[u*8+1]);
                pk[1] = cvt_pk(Br[u*8+2], Br[u*8+3]);
                pk[2] = cvt_pk(Br[u*8+4], Br[u*8+5]);
                pk[3] = cvt_pk(Br[u*8+6], Br[u*8+7]);
                int colb = (bkg * 16 + u * 8) * 2;
                *(u32x4*)((char*)Bs[bi] + bn * 128 + (colb ^ ((bn & 7) << 4))) = pk;
            }
        };

        // prologue: tile 0 -> buf 0
        issue_loads(0);
        cvt_store(0);
        __syncthreads();

        for (int s = 0; s < NS; ++s) {
            if (s + 1 < NS) issue_loads(s + 1);   // HBM latency hides under MFMA

            if (wact) {
                const char* Ab = (const char*)As[s & 1];
                const char* Bb = (const char*)Bs[s & 1];
                #pragma unroll
                for (int kk = 0; kk < 2; ++kk) {
                    int colb = kk * 64 + g * 16;
                    s16x8 af[4], bfr[2];
                    #pragma unroll
                    for (int mi = 0; mi < 4; ++mi) {
                        int m = wm * 64 + mi * 16 + (lane & 15);
                        af[mi] = *(const s16x8*)(Ab + m * 128 + (colb ^ ((m & 7) << 4)));
                    }
                    #pragma unroll
                    for (int ni = 0; ni < 2; ++ni) {
                        int n = wn * 32 + ni * 16 + (lane & 15);
                        bfr[ni] = *(const s16x8*)(Bb + n * 128 + (colb ^ ((n & 7) << 4)));
                    }
                    #pragma unroll
                    for (int mi = 0; mi < 4; ++mi)
                        #pragma unroll
                        for (int ni = 0; ni < 2; ++ni)
                            acc[mi][ni] = __builtin_amdgcn_mfma_f32_16x16x32_bf16(af[mi], bfr[ni], acc[mi][ni], 0, 0, 0);
                }
            }
            if (s + 1 < NS) cvt_store((s + 1) & 1);   // writes the OTHER buffer
            __syncthreads();                           // tile s+1 visible; buf s free next iter
        }

        // ---- epilogue: apply gate weight, bf16 scatter to per-(slot,kc) partial plane ----
        if (wact) {
            #pragma unroll
            for (int mi = 0; mi < 4; ++mi) {
                #pragma unroll
                for (int rg = 0; rg < 4; ++rg) {
                    int m = wm * 64 + mi * 16 + g * 4 + rg;
                    if (m < mloc) {
                        int ent = rowlist[e * NB + row0 + m];
                        float wgt = roww[e * NB + row0 + m];
                        int ob = ent >> 1, slot = ent & 1;
                        unsigned short* dst = ypart + ((size_t)(slot * nkc + kc) * NB + ob) * DOUT
                                            + nt * NT + wn * 32 + (lane & 15);
                        #pragma unroll
                        for (int ni = 0; ni < 2; ++ni)
                            dst[ni * 16] = f2bf_u(acc[mi][ni][rg] * wgt);
                    }
                }
            }
        }
        __syncthreads();   // LDS reuse safety before next row-tile prologue
    }
}

// ---------------- Kernel D: combine bf16 partial planes + weighted expert bias ------------
__global__ __launch_bounds__(256) void kcombine(
    const unsigned short* __restrict__ ypart,
    const int* __restrict__ top2e, const float* __restrict__ top2w,
    const float* __restrict__ eb, float* __restrict__ out, int nplanes)
{
    int b = blockIdx.y;
    int n = blockIdx.x * 256 + threadIdx.x;
    float s = 0.f;
    for (int p = 0; p < nplanes; ++p) {
        unsigned v = ypart[((size_t)p * NB + b) * DOUT + n];
        union { unsigned u; float f; } c; c.u = v << 16;
        s += c.f;
    }
    int e0 = top2e[b * 2], e1 = top2e[b * 2 + 1];
    float w0 = top2w[b * 2], w1 = top2w[b * 2 + 1];
    s += w0 * eb[e0 * DOUT + n] + w1 * eb[e1 * DOUT + n];
    out[(size_t)b * DOUT + n] = s;
}

extern "C" void kernel_launch(void* const* d_in, const int* in_sizes, int n_in,
                              void* d_out, int out_size, void* d_ws, size_t ws_size,
                              hipStream_t stream)
{
    const float* x   = (const float*)d_in[0];
    const float* gu  = (const float*)d_in[1];
    const float* cw  = (const float*)d_in[2];
    const float* cb  = (const float*)d_in[3];
    const float* bng = (const float*)d_in[4];
    const float* bnb = (const float*)d_in[5];
    const float* bnm = (const float*)d_in[6];
    const float* bnv = (const float*)d_in[7];
    const float* f1w = (const float*)d_in[8];
    const float* f1b = (const float*)d_in[9];
    const float* f2w = (const float*)d_in[10];
    const float* f2b = (const float*)d_in[11];
    const float* ew  = (const float*)d_in[12];
    const float* eb  = (const float*)d_in[13];

    int nkc = (ws_size >= (size_t)40 * 1024 * 1024) ? 16 : 8;
    int kch = DIN / nkc;

    char* ws = (char*)d_ws;
    size_t off = 0;
    float* h       = (float*)(ws + off); off += (size_t)NB * HD * 4;
    int*   top2e   = (int*)(ws + off);   off += (size_t)NB * 2 * 4;
    float* top2w   = (float*)(ws + off); off += (size_t)NB * 2 * 4;
    int*   cnt     = (int*)(ws + off);   off += 256;
    int*   rowlist = (int*)(ws + off);   off += (size_t)NE * NB * 4;
    float* roww    = (float*)(ws + off); off += (size_t)NE * NB * 4;
    unsigned short* ypart = (unsigned short*)(ws + off);
    off += (size_t)2 * nkc * NB * DOUT * 2;

    krouter_conv<<<NB, 512, 0, stream>>>(x, cw, cb, bng, bnb, bnm, bnv, h, cnt);
    krouter_fc<<<NB / 8, 256, 0, stream>>>(h, f1w, f1b, f2w, f2b, gu,
                                           top2e, top2w, cnt, rowlist, roww);
    kgemm<<<NE * 12 * nkc, 256, 0, stream>>>(x, ew, cnt, rowlist, roww, ypart, nkc, kch);
    kcombine<<<dim3(3, NB), 256, 0, stream>>>(ypart, top2e, top2w, eb, (float*)d_out, 2 * nkc);
}

// Round 6
// 276.613 us; speedup vs baseline: 1.2924x; 1.1420x over previous
//
#include <hip/hip_runtime.h>
#include <hip/hip_bf16.h>

#define NB 512
#define CIN 32
#define LEN 512
#define NE 8
#define NPOOL 16
#define DIN 16384
#define DOUT 768
#define HD 1024
#define F1 128

#define MT 128      // GEMM M tile
#define NT 128      // GEMM N tile
#define BK 32       // K step

typedef __attribute__((ext_vector_type(4))) float f32x4;
typedef __attribute__((ext_vector_type(8))) short s16x8;
typedef __attribute__((ext_vector_type(4))) unsigned int u32x4;

__device__ __forceinline__ float gelu_erf(float v) {
    return 0.5f * v * (1.0f + erff(v * 0.70710678118654752f));
}

__device__ __forceinline__ unsigned cvt_pk(float lo, float hi) {
    unsigned r;
    asm volatile("v_cvt_pk_bf16_f32 %0, %1, %2" : "=v"(r) : "v"(lo), "v"(hi));
    return r;
}

__device__ __forceinline__ unsigned short f2bf_u(float f) {
    union { float f; unsigned u; } x; x.f = f;
    unsigned r = x.u + 0x7fffu + ((x.u >> 16) & 1u);
    return (unsigned short)(r >> 16);
}

// async global->LDS DMA, 16B per lane, LDS dest = uniform base + lane*16
__device__ __forceinline__ void gload_lds16(const void* gptr, void* lptr) {
    __builtin_amdgcn_global_load_lds(
        (const __attribute__((address_space(1))) unsigned int*)gptr,
        (__attribute__((address_space(3))) unsigned int*)lptr,
        16, 0, 0);
}

// B LDS chunk swizzle: chunk' = chunk ^ sw(krel); spreads the 4 k-groups of a
// frag-read across both 16-bank halves -> 2-way (free).
__device__ __forceinline__ int bswz(int kr) {
    int g3 = kr >> 3;
    return (g3 & 3) | ((g3 & 1) << 2);
}

// ---------------- Kernel A: conv1d(k=3,pad=1) + GELU + avgpool(32) + BN ----------------
// grid (2 halves, 512 batch), block 256: half h covers pool bins h*8..h*8+7
__global__ __launch_bounds__(256) void krouter_conv(
    const float* __restrict__ x, const float* __restrict__ cw, const float* __restrict__ cb,
    const float* __restrict__ bng, const float* __restrict__ bnb,
    const float* __restrict__ bnm, const float* __restrict__ bnv,
    float* __restrict__ h, int* __restrict__ cnt)
{
    __shared__ float xs[CIN * 264];   // 33.8KB; 66 16B-chunks per ci, swizzled
    int half = blockIdx.x;
    int b = blockIdx.y;
    int t = threadIdx.x;
    if (b == 0 && half == 0 && t < NE) cnt[t] = 0;

    int Lchunk0 = half * 64 - 1;      // global chunk of local chunk 0
    const float* xb = x + (size_t)b * DIN;
    for (int idx = t; idx < CIN * 66; idx += 256) {
        int ci = idx / 66;
        int cc = idx - ci * 66;
        int gc = min(max(Lchunk0 + cc, 0), 127);
        f32x4 v = *(const f32x4*)(xb + ci * 512 + gc * 4);
        int byte = ci * 1056 + ((cc << 4) ^ (((cc >> 3) & 7) << 4));
        *(f32x4*)((char*)xs + byte) = v;
    }
    __syncthreads();

    int p  = t & 7;                   // local pool bin
    int pg = half * 8 + p;            // global pool bin
    int cq = t >> 3;                  // 0..31
    int co0 = cq * 2, co1 = co0 + 1;

    float sa[32], sb[32];
    #pragma unroll
    for (int i = 0; i < 32; ++i) { sa[i] = 0.f; sb[i] = 0.f; }

    for (int ci = 0; ci < CIN; ++ci) {
        float f[40];                  // f[i] = x[ci][pg*32 - 4 + i]
        #pragma unroll
        for (int u = 0; u < 10; ++u) {
            int lc = p * 8 + u;
            int byte = ci * 1056 + ((lc << 4) ^ (((lc >> 3) & 7) << 4));
            f32x4 v = *(const f32x4*)((const char*)xs + byte);
            f[4*u+0] = v[0]; f[4*u+1] = v[1]; f[4*u+2] = v[2]; f[4*u+3] = v[3];
        }
        if (pg == 0)  f[3]  = 0.f;
        if (pg == 15) f[36] = 0.f;
        float wa0 = cw[co0*96 + ci*3 + 0], wa1 = cw[co0*96 + ci*3 + 1], wa2 = cw[co0*96 + ci*3 + 2];
        float wb0 = cw[co1*96 + ci*3 + 0], wb1 = cw[co1*96 + ci*3 + 1], wb2 = cw[co1*96 + ci*3 + 2];
        #pragma unroll
        for (int i = 0; i < 32; ++i) {
            sa[i] = fmaf(f[i+3], wa0, fmaf(f[i+4], wa1, fmaf(f[i+5], wa2, sa[i])));
            sb[i] = fmaf(f[i+3], wb0, fmaf(f[i+4], wb1, fmaf(f[i+5], wb2, sb[i])));
        }
    }

    float ba = cb[co0], bbv = cb[co1];
    float ma = 0.f, mb = 0.f;
    #pragma unroll
    for (int i = 0; i < 32; ++i) { ma += gelu_erf(sa[i] + ba); mb += gelu_erf(sb[i] + bbv); }
    ma *= (1.f / 32.f); mb *= (1.f / 32.f);

    int oa = co0 * NPOOL + pg, ob = co1 * NPOOL + pg;
    float ra = (ma - bnm[oa]) * rsqrtf(bnv[oa] + 1e-5f) * bng[oa] + bnb[oa];
    float rb = (mb - bnm[ob]) * rsqrtf(bnv[ob] + 1e-5f) * bng[ob] + bnb[ob];
    h[(size_t)b * HD + oa] = ra;
    h[(size_t)b * HD + ob] = rb;
}

// ---------------- Kernel B: fc1+GELU, fc2, gumbel softmax, top-2, expert row lists ----------
__global__ __launch_bounds__(256) void krouter_fc(
    const float* __restrict__ h, const float* __restrict__ f1w, const float* __restrict__ f1b,
    const float* __restrict__ f2w, const float* __restrict__ f2b,
    const float* __restrict__ gu,
    int* __restrict__ top2e, float* __restrict__ top2w,
    int* __restrict__ cnt, int* __restrict__ rowlist, float* __restrict__ roww)
{
    __shared__ float hs[8 * HD];
    __shared__ float h1s[8 * F1];
    __shared__ float lg[8 * NE];

    int bb = blockIdx.x * 8;
    int t = threadIdx.x;

    const f32x4* hg = (const f32x4*)(h + (size_t)bb * HD);
    f32x4* hs4 = (f32x4*)hs;
    #pragma unroll
    for (int u = 0; u < 8; ++u) hs4[t + 256 * u] = hg[t + 256 * u];
    __syncthreads();

    int j = t & 127;
    int pr = t >> 7;
    float acc[4] = {0.f, 0.f, 0.f, 0.f};
    const f32x4* w4 = (const f32x4*)(f1w + (size_t)j * HD);
    for (int k4 = 0; k4 < 256; ++k4) {
        f32x4 w = w4[k4];
        #pragma unroll
        for (int g = 0; g < 4; ++g) {
            f32x4 hv = hs4[(pr * 4 + g) * 256 + k4];
            acc[g] += w[0]*hv[0] + w[1]*hv[1] + w[2]*hv[2] + w[3]*hv[3];
        }
    }
    float bj = f1b[j];
    #pragma unroll
    for (int g = 0; g < 4; ++g) h1s[(pr * 4 + g) * F1 + j] = gelu_erf(acc[g] + bj);
    __syncthreads();

    if (t < 64) {
        int bi = t >> 3, e = t & 7;
        float s = f2b[e];
        const float* w = f2w + e * F1;
        const float* hh = h1s + bi * F1;
        #pragma unroll 8
        for (int k = 0; k < F1; ++k) s += hh[k] * w[k];
        lg[bi * NE + e] = s;
    }
    __syncthreads();

    if (t < 8) {
        int bi = t; int b = bb + bi;
        float r[NE];
        float mx = -1e30f;
        #pragma unroll
        for (int e = 0; e < NE; ++e) {
            float g = -logf(-logf(gu[b * NE + e]));
            r[e] = lg[bi * NE + e] + g;
            mx = fmaxf(mx, r[e]);
        }
        float sum = 0.f;
        #pragma unroll
        for (int e = 0; e < NE; ++e) { r[e] = expf(r[e] - mx); sum += r[e]; }
        float inv = 1.f / sum;
        #pragma unroll
        for (int e = 0; e < NE; ++e) r[e] *= inv;
        int e0 = 0; float v0 = r[0];
        #pragma unroll
        for (int e = 1; e < NE; ++e) if (r[e] > v0) { v0 = r[e]; e0 = e; }
        int e1 = -1; float v1 = -1.f;
        #pragma unroll
        for (int e = 0; e < NE; ++e) { if (e == e0) continue; if (r[e] > v1) { v1 = r[e]; e1 = e; } }
        float den = v0 + v1 + 1e-8f;
        float w0 = v0 / den, w1 = v1 / den;
        top2e[b * 2 + 0] = e0; top2e[b * 2 + 1] = e1;
        top2w[b * 2 + 0] = w0; top2w[b * 2 + 1] = w1;
        int p0 = atomicAdd(&cnt[e0], 1);
        rowlist[e0 * NB + p0] = b * 2 + 0; roww[e0 * NB + p0] = w0;
        int p1 = atomicAdd(&cnt[e1], 1);
        rowlist[e1 * NB + p1] = b * 2 + 1; roww[e1 * NB + p1] = w1;
    }
}

// ---------------- Kernel C: gathered expert GEMM ----------------------------------------
// B (ew, the HBM stream) via global_load_lds DMA, fp32 in LDS, pre-swizzled source.
// A (x gather, L3-served) reg-staged -> bf16 LDS, XOR-swizzled.
// block 512 (8 waves 2m x 4n, wave tile 64x32); grid = 8e*6nt*16kc*2mt, mt pairs adjacent.
__global__ __launch_bounds__(512, 2) void kgemm(
    const float* __restrict__ x, const float* __restrict__ ew,
    const int* __restrict__ cnt, const int* __restrict__ rowlist, const float* __restrict__ roww,
    unsigned short* __restrict__ ypart, int nkc, int kch)
{
    int bid = blockIdx.x;
    int mt = bid & 1;
    int rest = bid >> 1;
    int kc = rest % nkc;
    int rest2 = rest / nkc;
    int nt = rest2 % 6;
    int e  = rest2 / 6;
    int cn = cnt[e];

    __shared__ __align__(16) char As[2][MT * BK * 2];   // 2 x 8KB  bf16 [m][k], 16B swz
    __shared__ __align__(16) char Bs[2][BK * NT * 4];   // 2 x 16KB fp32 [k][n-chunks swz]

    int t = threadIdx.x;
    int wid = t >> 6, lane = t & 63;
    int wm = wid >> 2, wn = wid & 3;
    int g = lane >> 4;
    int NS = kch / BK;
    int k0 = kc * kch;

    // --- B DMA per-lane source addresses (2 segments of 1KB per wave) ---
    int seg0 = wid * 2, seg1 = wid * 2 + 1;
    const char* gB = (const char*)ew + (size_t)e * DIN * DOUT * 4
                   + (size_t)k0 * (DOUT * 4) + nt * NT * 4;
    int kr0 = seg0 * 2 + (lane >> 5), cs0 = lane & 31;
    int kr1 = seg1 * 2 + (lane >> 5), cs1 = lane & 31;
    const char* gp0 = gB + (size_t)kr0 * (DOUT * 4) + ((cs0 ^ bswz(kr0)) << 4);
    const char* gp1 = gB + (size_t)kr1 * (DOUT * 4) + ((cs1 ^ bswz(kr1)) << 4);

    // --- A staging assignment: thread t -> row r = t>>2, k-quarter q = t&3 ---
    int ar = t >> 2, aq = t & 3;
    int aoff = ar * 64 + (((aq ^ (ar & 3))) << 4);

    for (int row0 = mt * MT; row0 < cn; row0 += 2 * MT) {
        int mloc = min(MT, cn - row0);
        int arc = min(ar, mloc - 1);
        int ent_a = rowlist[e * NB + row0 + arc];
        const float* axp = x + (size_t)(ent_a >> 1) * DIN + k0 + aq * 8;
        bool wact = (wm * 64 < mloc);

        f32x4 acc[4][2];
        #pragma unroll
        for (int i = 0; i < 4; ++i)
            #pragma unroll
            for (int jj = 0; jj < 2; ++jj) acc[i][jj] = (f32x4){0.f, 0.f, 0.f, 0.f};

        f32x4 a0, a1;
        const char* bp0 = gp0;
        const char* bp1 = gp1;

        auto stageB = [&](int bi) {
            gload_lds16(bp0, (char*)Bs[bi] + seg0 * 1024);
            gload_lds16(bp1, (char*)Bs[bi] + seg1 * 1024);
        };
        auto loadA = [&](int s) {
            const f32x4* p = (const f32x4*)(axp + (size_t)s * BK);
            a0 = p[0]; a1 = p[1];
        };
        auto storeA = [&](int bi) {
            u32x4 pk;
            pk[0] = cvt_pk(a0[0], a0[1]); pk[1] = cvt_pk(a0[2], a0[3]);
            pk[2] = cvt_pk(a1[0], a1[1]); pk[3] = cvt_pk(a1[2], a1[3]);
            *(u32x4*)(As[bi] + aoff) = pk;
        };

        // prologue: tile 0 -> buf 0
        stageB(0);
        loadA(0);
        storeA(0);
        __syncthreads();   // drains DMA + A stores visible

        for (int s = 0; s < NS; ++s) {
            int buf = s & 1;
            if (s + 1 < NS) {
                bp0 += BK * DOUT * 4;  bp1 += BK * DOUT * 4;
                stageB(buf ^ 1);       // async into other buffer
                loadA(s + 1);          // L3-latency hides under MFMA phase
            }

            if (wact) {
                const char* Ab = As[buf];
                const char* Bb = Bs[buf];
                s16x8 af[4];
                #pragma unroll
                for (int mi = 0; mi < 4; ++mi) {
                    int m = wm * 64 + mi * 16 + (lane & 15);
                    af[mi] = *(const s16x8*)(Ab + m * 64 + ((g ^ (m & 3)) << 4));
                }
                #pragma unroll
                for (int ni = 0; ni < 2; ++ni) {
                    int n = wn * 32 + ni * 16 + (lane & 15);
                    int sw = bswz(g * 8);                 // kr>>3 == g for all j
                    int cbase = (((n >> 2) ^ sw) << 4) + ((n & 3) << 2);
                    float v[8];
                    #pragma unroll
                    for (int j = 0; j < 8; ++j)
                        v[j] = *(const float*)(Bb + (g * 8 + j) * 512 + cbase);
                    union { u32x4 u; s16x8 s; } bf;
                    bf.u[0] = cvt_pk(v[0], v[1]); bf.u[1] = cvt_pk(v[2], v[3]);
                    bf.u[2] = cvt_pk(v[4], v[5]); bf.u[3] = cvt_pk(v[6], v[7]);
                    #pragma unroll
                    for (int mi = 0; mi < 4; ++mi)
                        acc[mi][ni] = __builtin_amdgcn_mfma_f32_16x16x32_bf16(af[mi], bf.s, acc[mi][ni], 0, 0, 0);
                }
            }

            if (s + 1 < NS) storeA(buf ^ 1);  // waits A loads (vmcnt counted past DMA)
            __syncthreads();                   // drains DMA for s+1; buffers swap
        }

        // ---- epilogue: gate weight, bf16 scatter to per-(slot,kc) partial plane ----
        if (wact) {
            #pragma unroll
            for (int mi = 0; mi < 4; ++mi) {
                #pragma unroll
                for (int rg = 0; rg < 4; ++rg) {
                    int m = wm * 64 + mi * 16 + g * 4 + rg;
                    if (m < mloc) {
                        int ent = rowlist[e * NB + row0 + m];
                        float wgt = roww[e * NB + row0 + m];
                        int ob = ent >> 1, slot = ent & 1;
                        unsigned short* dst = ypart + ((size_t)(slot * nkc + kc) * NB + ob) * DOUT
                                            + nt * NT + wn * 32 + (lane & 15);
                        #pragma unroll
                        for (int ni = 0; ni < 2; ++ni)
                            dst[ni * 16] = f2bf_u(acc[mi][ni][rg] * wgt);
                    }
                }
            }
        }
        __syncthreads();   // LDS safe before next (rare) row-tile
    }
}

// ---------------- Kernel D: combine bf16 partial planes + weighted expert bias ------------
__global__ __launch_bounds__(256) void kcombine(
    const unsigned short* __restrict__ ypart,
    const int* __restrict__ top2e, const float* __restrict__ top2w,
    const float* __restrict__ eb, float* __restrict__ out, int nplanes)
{
    int b = blockIdx.y;
    int n = blockIdx.x * 256 + threadIdx.x;
    float s = 0.f;
    for (int p = 0; p < nplanes; ++p) {
        unsigned v = ypart[((size_t)p * NB + b) * DOUT + n];
        union { unsigned u; float f; } c; c.u = v << 16;
        s += c.f;
    }
    int e0 = top2e[b * 2], e1 = top2e[b * 2 + 1];
    float w0 = top2w[b * 2], w1 = top2w[b * 2 + 1];
    s += w0 * eb[e0 * DOUT + n] + w1 * eb[e1 * DOUT + n];
    out[(size_t)b * DOUT + n] = s;
}

extern "C" void kernel_launch(void* const* d_in, const int* in_sizes, int n_in,
                              void* d_out, int out_size, void* d_ws, size_t ws_size,
                              hipStream_t stream)
{
    const float* x   = (const float*)d_in[0];
    const float* gu  = (const float*)d_in[1];
    const float* cw  = (const float*)d_in[2];
    const float* cb  = (const float*)d_in[3];
    const float* bng = (const float*)d_in[4];
    const float* bnb = (const float*)d_in[5];
    const float* bnm = (const float*)d_in[6];
    const float* bnv = (const float*)d_in[7];
    const float* f1w = (const float*)d_in[8];
    const float* f1b = (const float*)d_in[9];
    const float* f2w = (const float*)d_in[10];
    const float* f2b = (const float*)d_in[11];
    const float* ew  = (const float*)d_in[12];
    const float* eb  = (const float*)d_in[13];

    int nkc = (ws_size >= (size_t)40 * 1024 * 1024) ? 16 : 8;
    int kch = DIN / nkc;

    char* ws = (char*)d_ws;
    size_t off = 0;
    float* h       = (float*)(ws + off); off += (size_t)NB * HD * 4;
    int*   top2e   = (int*)(ws + off);   off += (size_t)NB * 2 * 4;
    float* top2w   = (float*)(ws + off); off += (size_t)NB * 2 * 4;
    int*   cnt     = (int*)(ws + off);   off += 256;
    int*   rowlist = (int*)(ws + off);   off += (size_t)NE * NB * 4;
    float* roww    = (float*)(ws + off); off += (size_t)NE * NB * 4;
    unsigned short* ypart = (unsigned short*)(ws + off);
    off += (size_t)2 * nkc * NB * DOUT * 2;

    krouter_conv<<<dim3(2, NB), 256, 0, stream>>>(x, cw, cb, bng, bnb, bnm, bnv, h, cnt);
    krouter_fc<<<NB / 8, 256, 0, stream>>>(h, f1w, f1b, f2w, f2b, gu,
                                           top2e, top2w, cnt, rowlist, roww);
    kgemm<<<NE * 6 * nkc * 2, 512, 0, stream>>>(x, ew, cnt, rowlist, roww, ypart, nkc, kch);
    kcombine<<<dim3(3, NB), 256, 0, stream>>>(ypart, top2e, top2w, eb, (float*)d_out, 2 * nkc);
}

// Round 7
// 237.871 us; speedup vs baseline: 1.5029x; 1.1629x over previous
//
#include <hip/hip_runtime.h>
#include <hip/hip_bf16.h>

#define NB 512
#define CIN 32
#define LEN 512
#define NE 8
#define NPOOL 16
#define DIN 16384
#define DOUT 768
#define HD 1024
#define F1 128

#define MT 256      // GEMM M tile (covers whole expert; loop if cn>256)
#define NT 96       // GEMM N tile (8 n-tiles over DOUT=768)
#define BK 32       // K step

typedef __attribute__((ext_vector_type(4))) float f32x4;
typedef __attribute__((ext_vector_type(8))) short s16x8;
typedef __attribute__((ext_vector_type(4))) unsigned int u32x4;

__device__ __forceinline__ float gelu_erf(float v) {
    return 0.5f * v * (1.0f + erff(v * 0.70710678118654752f));
}

__device__ __forceinline__ unsigned cvt_pk(float lo, float hi) {
    unsigned r;
    asm volatile("v_cvt_pk_bf16_f32 %0, %1, %2" : "=v"(r) : "v"(lo), "v"(hi));
    return r;
}

__device__ __forceinline__ unsigned short f2bf_u(float f) {
    union { float f; unsigned u; } x; x.f = f;
    unsigned r = x.u + 0x7fffu + ((x.u >> 16) & 1u);
    return (unsigned short)(r >> 16);
}

// async global->LDS DMA, 16B/lane, LDS dest = wave-uniform base + lane*16
__device__ __forceinline__ void gload_lds16(const void* gptr, void* lptr) {
    __builtin_amdgcn_global_load_lds(
        (const __attribute__((address_space(1))) unsigned int*)gptr,
        (__attribute__((address_space(3))) unsigned int*)lptr,
        16, 0, 0);
}

// B LDS chunk swizzle key per k-row (spreads frag reads 2-way -> free)
__device__ __forceinline__ int bswz(int k) {
    int g3 = k >> 3;
    return (g3 & 3) | ((g3 & 1) << 2);
}
// A LDS chunk swizzle key per m-row (even bank coverage on store & read)
__device__ __forceinline__ int akey(int m) {
    return (m & 3) ^ ((m >> 2) & 3);
}

// ---------------- Kernel A: conv1d(k=3,pad=1) + GELU + avgpool(32) + BN ----------------
__global__ __launch_bounds__(256) void krouter_conv(
    const float* __restrict__ x, const float* __restrict__ cw, const float* __restrict__ cb,
    const float* __restrict__ bng, const float* __restrict__ bnb,
    const float* __restrict__ bnm, const float* __restrict__ bnv,
    float* __restrict__ h, int* __restrict__ cnt)
{
    __shared__ float xs[CIN * 264];
    int half = blockIdx.x;
    int b = blockIdx.y;
    int t = threadIdx.x;
    if (b == 0 && half == 0 && t < NE) cnt[t] = 0;

    int Lchunk0 = half * 64 - 1;
    const float* xb = x + (size_t)b * DIN;
    for (int idx = t; idx < CIN * 66; idx += 256) {
        int ci = idx / 66;
        int cc = idx - ci * 66;
        int gc = min(max(Lchunk0 + cc, 0), 127);
        f32x4 v = *(const f32x4*)(xb + ci * 512 + gc * 4);
        int byte = ci * 1056 + ((cc << 4) ^ (((cc >> 3) & 7) << 4));
        *(f32x4*)((char*)xs + byte) = v;
    }
    __syncthreads();

    int p  = t & 7;
    int pg = half * 8 + p;
    int cq = t >> 3;
    int co0 = cq * 2, co1 = co0 + 1;

    float sa[32], sb[32];
    #pragma unroll
    for (int i = 0; i < 32; ++i) { sa[i] = 0.f; sb[i] = 0.f; }

    for (int ci = 0; ci < CIN; ++ci) {
        float f[40];
        #pragma unroll
        for (int u = 0; u < 10; ++u) {
            int lc = p * 8 + u;
            int byte = ci * 1056 + ((lc << 4) ^ (((lc >> 3) & 7) << 4));
            f32x4 v = *(const f32x4*)((const char*)xs + byte);
            f[4*u+0] = v[0]; f[4*u+1] = v[1]; f[4*u+2] = v[2]; f[4*u+3] = v[3];
        }
        if (pg == 0)  f[3]  = 0.f;
        if (pg == 15) f[36] = 0.f;
        float wa0 = cw[co0*96 + ci*3 + 0], wa1 = cw[co0*96 + ci*3 + 1], wa2 = cw[co0*96 + ci*3 + 2];
        float wb0 = cw[co1*96 + ci*3 + 0], wb1 = cw[co1*96 + ci*3 + 1], wb2 = cw[co1*96 + ci*3 + 2];
        #pragma unroll
        for (int i = 0; i < 32; ++i) {
            sa[i] = fmaf(f[i+3], wa0, fmaf(f[i+4], wa1, fmaf(f[i+5], wa2, sa[i])));
            sb[i] = fmaf(f[i+3], wb0, fmaf(f[i+4], wb1, fmaf(f[i+5], wb2, sb[i])));
        }
    }

    float ba = cb[co0], bbv = cb[co1];
    float ma = 0.f, mb = 0.f;
    #pragma unroll
    for (int i = 0; i < 32; ++i) { ma += gelu_erf(sa[i] + ba); mb += gelu_erf(sb[i] + bbv); }
    ma *= (1.f / 32.f); mb *= (1.f / 32.f);

    int oa = co0 * NPOOL + pg, ob = co1 * NPOOL + pg;
    float ra = (ma - bnm[oa]) * rsqrtf(bnv[oa] + 1e-5f) * bng[oa] + bnb[oa];
    float rb = (mb - bnm[ob]) * rsqrtf(bnv[ob] + 1e-5f) * bng[ob] + bnb[ob];
    h[(size_t)b * HD + oa] = ra;
    h[(size_t)b * HD + ob] = rb;
}

// ---------------- Kernel B: fc1+GELU, fc2, gumbel softmax, top-2, expert row lists ----------
__global__ __launch_bounds__(256) void krouter_fc(
    const float* __restrict__ h, const float* __restrict__ f1w, const float* __restrict__ f1b,
    const float* __restrict__ f2w, const float* __restrict__ f2b,
    const float* __restrict__ gu,
    int* __restrict__ top2e, float* __restrict__ top2w,
    int* __restrict__ cnt, int* __restrict__ rowlist, float* __restrict__ roww)
{
    __shared__ float hs[8 * HD];
    __shared__ float h1s[8 * F1];
    __shared__ float lg[8 * NE];

    int bb = blockIdx.x * 8;
    int t = threadIdx.x;

    const f32x4* hg = (const f32x4*)(h + (size_t)bb * HD);
    f32x4* hs4 = (f32x4*)hs;
    #pragma unroll
    for (int u = 0; u < 8; ++u) hs4[t + 256 * u] = hg[t + 256 * u];
    __syncthreads();

    int j = t & 127;
    int pr = t >> 7;
    float acc[4] = {0.f, 0.f, 0.f, 0.f};
    const f32x4* w4 = (const f32x4*)(f1w + (size_t)j * HD);
    for (int k4 = 0; k4 < 256; ++k4) {
        f32x4 w = w4[k4];
        #pragma unroll
        for (int g = 0; g < 4; ++g) {
            f32x4 hv = hs4[(pr * 4 + g) * 256 + k4];
            acc[g] += w[0]*hv[0] + w[1]*hv[1] + w[2]*hv[2] + w[3]*hv[3];
        }
    }
    float bj = f1b[j];
    #pragma unroll
    for (int g = 0; g < 4; ++g) h1s[(pr * 4 + g) * F1 + j] = gelu_erf(acc[g] + bj);
    __syncthreads();

    if (t < 64) {
        int bi = t >> 3, e = t & 7;
        float s = f2b[e];
        const float* w = f2w + e * F1;
        const float* hh = h1s + bi * F1;
        #pragma unroll 8
        for (int k = 0; k < F1; ++k) s += hh[k] * w[k];
        lg[bi * NE + e] = s;
    }
    __syncthreads();

    if (t < 8) {
        int bi = t; int b = bb + bi;
        float r[NE];
        float mx = -1e30f;
        #pragma unroll
        for (int e = 0; e < NE; ++e) {
            float g = -logf(-logf(gu[b * NE + e]));
            r[e] = lg[bi * NE + e] + g;
            mx = fmaxf(mx, r[e]);
        }
        float sum = 0.f;
        #pragma unroll
        for (int e = 0; e < NE; ++e) { r[e] = expf(r[e] - mx); sum += r[e]; }
        float inv = 1.f / sum;
        #pragma unroll
        for (int e = 0; e < NE; ++e) r[e] *= inv;
        int e0 = 0; float v0 = r[0];
        #pragma unroll
        for (int e = 1; e < NE; ++e) if (r[e] > v0) { v0 = r[e]; e0 = e; }
        int e1 = -1; float v1 = -1.f;
        #pragma unroll
        for (int e = 0; e < NE; ++e) { if (e == e0) continue; if (r[e] > v1) { v1 = r[e]; e1 = e; } }
        float den = v0 + v1 + 1e-8f;
        float w0 = v0 / den, w1 = v1 / den;
        top2e[b * 2 + 0] = e0; top2e[b * 2 + 1] = e1;
        top2w[b * 2 + 0] = w0; top2w[b * 2 + 1] = w1;
        int p0 = atomicAdd(&cnt[e0], 1);
        rowlist[e0 * NB + p0] = b * 2 + 0; roww[e0 * NB + p0] = w0;
        int p1 = atomicAdd(&cnt[e1], 1);
        rowlist[e1 * NB + p1] = b * 2 + 1; roww[e1 * NB + p1] = w1;
    }
}

// ---------------- Kernel C: gathered expert GEMM ----------------------------------------
// MT=256 (whole expert), NT=96, BK=32. B via global_load_lds DMA (fp32 LDS, pre-swizzled
// src). A reg-staged -> bf16 LDS. Order: loadA(s+1), stageB(s+1) DMA, storeA (waits A only,
// DMA stays in flight), MFMA, one barrier. Grid 1024 = 8e*16kc*8nt, XCD-chunk swizzled.
__global__ __launch_bounds__(512, 2) void kgemm(
    const float* __restrict__ x, const float* __restrict__ ew,
    const int* __restrict__ cnt, const int* __restrict__ rowlist, const float* __restrict__ roww,
    unsigned short* __restrict__ ypart, int nkc, int kch)
{
    // bijective XCD-chunk swizzle: each XCD gets contiguous wg range = one expert
    int nwg = gridDim.x;
    int cpx = nwg >> 3;
    int wg = (blockIdx.x & 7) * cpx + (blockIdx.x >> 3);
    int nt = wg & 7;
    int kc = (wg >> 3) % nkc;
    int e  = wg / (8 * nkc);
    int cn = cnt[e];

    __shared__ __align__(16) char As[2][MT * BK * 2];   // 2 x 16KB bf16 [m][k], chunk-swz
    __shared__ __align__(16) char Bs[2][BK * NT * 4];   // 2 x 12KB fp32 [k][n-chunks swz]

    int t = threadIdx.x;
    int wid = t >> 6, lane = t & 63;
    int wm = wid >> 1, wn = wid & 1;
    int g = lane >> 4;
    int NS = kch / BK;
    int k0 = kc * kch;

    // --- B DMA per-lane source addrs: 12 segs of 1KB; waves 0-3 take 2, 4-7 take 1 ---
    const char* gB = (const char*)ew + (size_t)e * DIN * DOUT * 4
                   + (size_t)k0 * (DOUT * 4) + nt * NT * 4;
    int seg0 = wid;
    int seg1 = (wid < 4) ? (8 + wid) : -1;
    int off0 = seg0 * 1024 + lane * 16;
    int k_0 = off0 / 384, c_0 = (off0 - k_0 * 384) >> 4;
    const char* gp0 = gB + (size_t)k_0 * (DOUT * 4) + ((c_0 ^ bswz(k_0)) << 4);
    const char* gp1 = nullptr;
    int ldsoff1 = 0;
    if (seg1 >= 0) {
        int off1 = seg1 * 1024 + lane * 16;
        int k_1 = off1 / 384, c_1 = (off1 - k_1 * 384) >> 4;
        gp1 = gB + (size_t)k_1 * (DOUT * 4) + ((c_1 ^ bswz(k_1)) << 4);
        ldsoff1 = seg1 * 1024;
    }
    int ldsoff0 = seg0 * 1024;

    // --- A staging: thread t -> row t>>1 (0..255), half t&1 (16 floats) ---
    int ar = t >> 1, ah = t & 1;
    int arow_byte = ar * 64;
    int ak = akey(ar);
    int ac0 = ((2 * ah) ^ ak) << 4;
    int ac1 = ((2 * ah + 1) ^ ak) << 4;

    for (int row0 = 0; row0 < cn; row0 += MT) {
        int mloc = min(MT, cn - row0);
        int arc = min(ar, mloc - 1);
        int ent_a = rowlist[e * NB + row0 + arc];
        const float* axp = x + (size_t)(ent_a >> 1) * DIN + k0 + ah * 16;
        bool wact = (wm * 64 < mloc);

        f32x4 acc[4][3];
        #pragma unroll
        for (int i = 0; i < 4; ++i)
            #pragma unroll
            for (int jj = 0; jj < 3; ++jj) acc[i][jj] = (f32x4){0.f, 0.f, 0.f, 0.f};

        f32x4 a0, a1, a2, a3;
        const char* bp0 = gp0;
        const char* bp1 = gp1;

        auto loadA = [&](int s) {
            const f32x4* p = (const f32x4*)(axp + (size_t)s * BK);
            a0 = p[0]; a1 = p[1]; a2 = p[2]; a3 = p[3];
        };
        auto stageB = [&](int bi) {
            gload_lds16(bp0, (char*)Bs[bi] + ldsoff0);
            if (seg1 >= 0) gload_lds16(bp1, (char*)Bs[bi] + ldsoff1);
        };
        auto storeA = [&](int bi) {
            u32x4 pk0, pk1;
            pk0[0] = cvt_pk(a0[0], a0[1]); pk0[1] = cvt_pk(a0[2], a0[3]);
            pk0[2] = cvt_pk(a1[0], a1[1]); pk0[3] = cvt_pk(a1[2], a1[3]);
            pk1[0] = cvt_pk(a2[0], a2[1]); pk1[1] = cvt_pk(a2[2], a2[3]);
            pk1[2] = cvt_pk(a3[0], a3[1]); pk1[3] = cvt_pk(a3[2], a3[3]);
            *(u32x4*)(As[bi] + arow_byte + ac0) = pk0;
            *(u32x4*)(As[bi] + arow_byte + ac1) = pk1;
        };

        // prologue: tile 0 -> buf 0
        loadA(0);
        stageB(0);
        storeA(0);
        __syncthreads();

        for (int s = 0; s < NS; ++s) {
            int buf = s & 1;
            if (s + 1 < NS) {
                loadA(s + 1);                      // A first (older in vmcnt queue)
                bp0 += BK * DOUT * 4;
                if (seg1 >= 0) bp1 += BK * DOUT * 4;
                stageB(buf ^ 1);                   // DMA stays in flight through MFMA
                storeA(buf ^ 1);                   // waits A loads only (counted vmcnt)
            }

            if (wact) {
                const char* Ab = As[buf];
                const char* Bb = Bs[buf];
                s16x8 af[4];
                #pragma unroll
                for (int mi = 0; mi < 4; ++mi) {
                    int m = wm * 64 + mi * 16 + (lane & 15);
                    af[mi] = *(const s16x8*)(Ab + m * 64 + ((g ^ akey(m)) << 4));
                }
                int key = bswz(g * 8);
                #pragma unroll
                for (int ni = 0; ni < 3; ++ni) {
                    int n = wn * 48 + ni * 16 + (lane & 15);
                    int cbase = (((n >> 2) ^ key) << 4) + ((n & 3) << 2);
                    float v[8];
                    #pragma unroll
                    for (int j = 0; j < 8; ++j)
                        v[j] = *(const float*)(Bb + (g * 8 + j) * 384 + cbase);
                    union { u32x4 u; s16x8 s; } bf;
                    bf.u[0] = cvt_pk(v[0], v[1]); bf.u[1] = cvt_pk(v[2], v[3]);
                    bf.u[2] = cvt_pk(v[4], v[5]); bf.u[3] = cvt_pk(v[6], v[7]);
                    #pragma unroll
                    for (int mi = 0; mi < 4; ++mi)
                        acc[mi][ni] = __builtin_amdgcn_mfma_f32_16x16x32_bf16(af[mi], bf.s, acc[mi][ni], 0, 0, 0);
                }
            }
            __syncthreads();   // drains DMA (aged through MFMA phase); swap buffers
        }

        // ---- epilogue: gate weight, bf16 scatter to per-(slot,kc) partial plane ----
        if (wact) {
            #pragma unroll
            for (int mi = 0; mi < 4; ++mi) {
                #pragma unroll
                for (int rg = 0; rg < 4; ++rg) {
                    int m = wm * 64 + mi * 16 + g * 4 + rg;
                    if (m < mloc) {
                        int ent = rowlist[e * NB + row0 + m];
                        float wgt = roww[e * NB + row0 + m];
                        int ob = ent >> 1, slot = ent & 1;
                        unsigned short* dst = ypart + ((size_t)(slot * nkc + kc) * NB + ob) * DOUT
                                            + nt * NT + wn * 48 + (lane & 15);
                        #pragma unroll
                        for (int ni = 0; ni < 3; ++ni)
                            dst[ni * 16] = f2bf_u(acc[mi][ni][rg] * wgt);
                    }
                }
            }
        }
    }
}

// ---------------- Kernel D: combine bf16 partial planes + weighted expert bias ------------
__global__ __launch_bounds__(256) void kcombine(
    const unsigned short* __restrict__ ypart,
    const int* __restrict__ top2e, const float* __restrict__ top2w,
    const float* __restrict__ eb, float* __restrict__ out, int nplanes)
{
    int b = blockIdx.y;
    int n = blockIdx.x * 256 + threadIdx.x;
    float s = 0.f;
    for (int p = 0; p < nplanes; ++p) {
        unsigned v = ypart[((size_t)p * NB + b) * DOUT + n];
        union { unsigned u; float f; } c; c.u = v << 16;
        s += c.f;
    }
    int e0 = top2e[b * 2], e1 = top2e[b * 2 + 1];
    float w0 = top2w[b * 2], w1 = top2w[b * 2 + 1];
    s += w0 * eb[e0 * DOUT + n] + w1 * eb[e1 * DOUT + n];
    out[(size_t)b * DOUT + n] = s;
}

extern "C" void kernel_launch(void* const* d_in, const int* in_sizes, int n_in,
                              void* d_out, int out_size, void* d_ws, size_t ws_size,
                              hipStream_t stream)
{
    const float* x   = (const float*)d_in[0];
    const float* gu  = (const float*)d_in[1];
    const float* cw  = (const float*)d_in[2];
    const float* cb  = (const float*)d_in[3];
    const float* bng = (const float*)d_in[4];
    const float* bnb = (const float*)d_in[5];
    const float* bnm = (const float*)d_in[6];
    const float* bnv = (const float*)d_in[7];
    const float* f1w = (const float*)d_in[8];
    const float* f1b = (const float*)d_in[9];
    const float* f2w = (const float*)d_in[10];
    const float* f2b = (const float*)d_in[11];
    const float* ew  = (const float*)d_in[12];
    const float* eb  = (const float*)d_in[13];

    int nkc = (ws_size >= (size_t)40 * 1024 * 1024) ? 16 : 8;
    int kch = DIN / nkc;

    char* ws = (char*)d_ws;
    size_t off = 0;
    float* h       = (float*)(ws + off); off += (size_t)NB * HD * 4;
    int*   top2e   = (int*)(ws + off);   off += (size_t)NB * 2 * 4;
    float* top2w   = (float*)(ws + off); off += (size_t)NB * 2 * 4;
    int*   cnt     = (int*)(ws + off);   off += 256;
    int*   rowlist = (int*)(ws + off);   off += (size_t)NE * NB * 4;
    float* roww    = (float*)(ws + off); off += (size_t)NE * NB * 4;
    unsigned short* ypart = (unsigned short*)(ws + off);
    off += (size_t)2 * nkc * NB * DOUT * 2;

    krouter_conv<<<dim3(2, NB), 256, 0, stream>>>(x, cw, cb, bng, bnb, bnm, bnv, h, cnt);
    krouter_fc<<<NB / 8, 256, 0, stream>>>(h, f1w, f1b, f2w, f2b, gu,
                                           top2e, top2w, cnt, rowlist, roww);
    kgemm<<<NE * nkc * 8, 512, 0, stream>>>(x, ew, cnt, rowlist, roww, ypart, nkc, kch);
    kcombine<<<dim3(3, NB), 256, 0, stream>>>(ypart, top2e, top2w, eb, (float*)d_out, 2 * nkc);
}